// Round 11
// baseline (703.535 us; speedup 1.0000x reference)
//
#include <hip/hip_runtime.h>
#include <hip/hip_bf16.h>

// NARX RNN. Inputs fp32, compute bf16 MFMA 16x16x32, output fp32.
// SKEWED schedule (u(s) once per slice, advance all active chains) +
// factored axh = bh + Wxh.u (R6 structure, verified spill-free/clean).
// R11: __launch_bounds__(256, 8) -- the single change vs R6.
//   Every prior failure (R1/R5/R7/R9) was a collision with the launch-
//   bounds register cap; R8/R10's LDS-eviction machinery (weights->LDS,
//   per-slice clobbers, h-ring) existed only to fit 102-170 regs. The
//   per-SIMD VGPR pool is 2048 with 64-granule allocation: R6's ~170-reg
//   demand allocates <=256 -> 2048/256 = 8 waves/SIMD (HW max) with NO
//   eviction. LDS back to s_win only (5KB) -> 8 blocks/CU wave-capped.
//   4064 blocks / 2048 in flight = 1.98 rounds -> near-zero drain tail
//   (vs 3.2 rounds at 5 blocks/CU).
// Layout math (verified R0-R10):
//   C/D layout: lane (col=lane&15, q=lane>>4) holds rows 16tn+4q+r; natural
//   pair packing + pi(p)-permuted W^T staging makes packed frags valid as
//   next B operand. pi(p) = 32(p>>5)+16((p>>2)&1)+4((p>>3)&3)+(p&3).
//   bin folded into u-MFMA K slot 16 (q==2 lanes carry bf16(1.0)).
// s_win stride 40; pad slots 17..31 zeroed. 2*log2(e) folded into weights.
// tanh = raw v_exp + rcp (pre-scaled input; graceful underflow).

#define NG    2048
#define NXF   16
#define HIDN  64
#define DLAG  4
#define TOUTN 508
#define GBLK  64    // g rows per block (4 waves x 16)
#define TTB   4     // outputs per block
#define NSLC  (DLAG + TTB - 1)   // 7 slices per block
#define STR   72    // setup-kernel staging stride (shorts)
#define SW    40    // resident Win^T stride (shorts), 80B = 16B-aligned rows
#define SCALE 2.8853900817779268f   // 2*log2(e)
#define WXH_OFF 0       // ws offsets in shorts
#define WHH_OFF 4096
#define BH_OFF  8192    // scaled bh, fp32

typedef short  s16x8 __attribute__((ext_vector_type(8)));
typedef float  f32x4 __attribute__((ext_vector_type(4)));
typedef unsigned int u32x4 __attribute__((ext_vector_type(4)));

__device__ __forceinline__ unsigned short f2bf(float f) {  // RTNE (init only)
    unsigned int u = __float_as_uint(f);
    u += 0x7fffu + ((u >> 16) & 1u);
    return (unsigned short)(u >> 16);
}
__device__ __forceinline__ unsigned int pk2bf(float a, float b) {  // [lo=a, hi=b]
    union { __hip_bfloat162 h2; unsigned int u; } c;
    c.h2 = __float22bfloat162_rn(float2{a, b});
    return c.u;
}
__device__ __forceinline__ float raw_exp2(float a) {
#if __has_builtin(__builtin_amdgcn_exp2f)
    return __builtin_amdgcn_exp2f(a);
#else
    float r;
    asm("v_exp_f32 %0, %1" : "=v"(r) : "v"(a));
    return r;
#endif
}
__device__ __forceinline__ float tanh_pre(float a) {
    // a is already scaled by 2*log2(e) (folded into weights/bias)
    float e = raw_exp2(a);
    return fmaf(-2.0f, __builtin_amdgcn_rcpf(e + 1.0f), 1.0f);
}

// ---- setup: pack Wxh/Whh MFMA fragments (pi-permuted, scaled) + scaled bh ----
__global__ __launch_bounds__(256, 1)
void pack_weights(const float* __restrict__ Wxh,
                  const float* __restrict__ Whh,
                  const float* __restrict__ bh,
                  unsigned short* __restrict__ ws)
{
    __shared__ unsigned short s_stage[HIDN * STR];
    const int tid  = threadIdx.x;
    const int lane = tid & 63;
    const int lm   = lane & 15;
    const int q    = lane >> 4;
    const int p0   = tid >> 2;
    const int pi0  = 32*(p0>>5) + 16*((p0>>2)&1) + 4*((p0>>3)&3) + (p0&3);
    const int n0   = (tid & 3) * 16;

    if (tid < 64) {
        float* bhs = (float*)(ws + BH_OFF);
        bhs[tid] = bh[tid] * SCALE;
    }

    {
        const float* src = Wxh + pi0 * HIDN + n0;
        #pragma unroll
        for (int i = 0; i < 16; ++i)
            s_stage[(n0 + i) * STR + p0] = f2bf(src[i] * SCALE);
    }
    __syncthreads();
    if (tid < 64) {
        #pragma unroll
        for (int tn = 0; tn < 4; ++tn)
            #pragma unroll
            for (int kk = 0; kk < 2; ++kk)
                *(s16x8*)&ws[WXH_OFF + lane*64 + tn*16 + kk*8] =
                    *(const s16x8*)&s_stage[(tn*16 + lm) * STR + kk*32 + q*8];
    }
    __syncthreads();
    {
        const float* src = Whh + pi0 * HIDN + n0;
        #pragma unroll
        for (int i = 0; i < 16; ++i)
            s_stage[(n0 + i) * STR + p0] = f2bf(src[i] * SCALE);
    }
    __syncthreads();
    if (tid < 64) {
        #pragma unroll
        for (int tn = 0; tn < 4; ++tn)
            #pragma unroll
            for (int kk = 0; kk < 2; ++kk)
                *(s16x8*)&ws[WHH_OFF + lane*64 + tn*16 + kk*8] =
                    *(const s16x8*)&s_stage[(tn*16 + lm) * STR + kk*32 + q*8];
    }
}

__global__ __launch_bounds__(256, 8)
void narx_kernel(const float* __restrict__ x,
                 const float* __restrict__ Win,
                 const float* __restrict__ bin_g,
                 const unsigned short* __restrict__ wfrag,
                 const float* __restrict__ Wout,
                 const float* __restrict__ bout_g,
                 float* __restrict__ out)
{
    __shared__ unsigned short s_win[HIDN * SW];     // resident Win^T + bin row

    const int tid   = threadIdx.x;
    const int lane  = tid & 63;
    const int lm    = lane & 15;
    const int q     = lane >> 4;
    const int G0    = blockIdx.x * GBLK;
    const int tt0   = blockIdx.y * TTB;
    const int wrow0 = (tid >> 6) * 16;
    const int myg   = G0 + wrow0 + lm;

    // zero the t<DLAG head of the output (poisoned before every launch)
    if (blockIdx.y == 0 && tid < GBLK) {
        #pragma unroll
        for (int t2 = 0; t2 < DLAG; ++t2)
            out[t2 * NG + G0 + tid] = 0.0f;
    }

    // ---- load prepacked Wxh/Whh fragments (coalesced dwordx4, L2-hit) ----
    s16x8 wxhf[4][2], whhf[4][2];
    #pragma unroll
    for (int tn = 0; tn < 4; ++tn)
        #pragma unroll
        for (int kk = 0; kk < 2; ++kk) {
            wxhf[tn][kk] = *(const s16x8*)&wfrag[WXH_OFF + lane*64 + tn*16 + kk*8];
            whhf[tn][kk] = *(const s16x8*)&wfrag[WHH_OFF + lane*64 + tn*16 + kk*8];
        }
    const float* bhs = (const float*)(wfrag + BH_OFF);   // scaled bh (fp32)

    // ---- build s_win: slots k<16 = Win^T, slot 16 = bin, 17..31 = 0 ----
    {
        int r = tid >> 2, c0 = 16 + (tid & 3) * 4;
        #pragma unroll
        for (int i = 0; i < 4; ++i) {
            unsigned short v = 0;
            if (c0 + i == 16) v = f2bf(bin_g[r]);
            s_win[r * SW + c0 + i] = v;
        }
    }
    {
        int k = tid >> 4, nn = (tid & 15) * 4;
        const float* src = Win + k * HIDN + nn;
        #pragma unroll
        for (int i = 0; i < 4; ++i) s_win[(nn + i) * SW + k] = f2bf(src[i]);
    }

    const float boutf = bout_g[0];
    __syncthreads();   // s_win fully written

    // ---- skewed hot loop over slices tt0 .. tt0+6 ----
    const size_t slcstride = (size_t)NG * NXF;
    const float* px = x + ((size_t)tt0 * NG + myg) * NXF + q * 8;

    // load + pack slice s into a ready B-frag (q==2 carries the bias 1.0)
    auto load_pack = [&](int s) -> s16x8 {
        s16x8 r = {0,0,0,0,0,0,0,0};
        if (q == 2) r[0] = (short)0x3F80;   // bf16(1.0) at k=16 -> +bin
        if (q < 2) {   // features k = q*8+j < 16
            const float* p = px + (size_t)s * slcstride;
            f32x4 a = *(const f32x4*)p;
            f32x4 b = *(const f32x4*)(p + 4);
            u32x4 xi;
            xi[0] = pk2bf(a[0], a[1]);
            xi[1] = pk2bf(a[2], a[3]);
            xi[2] = pk2bf(b[0], b[1]);
            xi[3] = pk2bf(b[2], b[3]);
            r = __builtin_bit_cast(s16x8, xi);
        }
        return r;
    };

    u32x4 hpk[TTB][2];   // packed h per output chain (= next step's B-frags)
    s16x8 xf = load_pack(0);

    #pragma unroll
    for (int s = 0; s < NSLC; ++s) {
        // prefetch+pack slice s+1 (independent; lands during this compute)
        s16x8 xf_nxt = xf;
        if (s + 1 < NSLC) xf_nxt = load_pack(s + 1);

        // ---- u(s) = relu(x_s @ Win + bin), computed once, packed bf16 ----
        u32x4 upk[2];
        #pragma unroll
        for (int tj = 0; tj < 4; ++tj) {
            s16x8 wf = *(const s16x8*)&s_win[(tj*16 + lm) * SW + q*8];
            f32x4 zc = {0.f, 0.f, 0.f, 0.f};
            f32x4 ua = __builtin_amdgcn_mfma_f32_16x16x32_bf16(wf, xf, zc, 0, 0, 0);
            upk[tj>>1][(tj&1)*2+0] = pk2bf(fmaxf(ua[0],0.f), fmaxf(ua[1],0.f));
            upk[tj>>1][(tj&1)*2+1] = pk2bf(fmaxf(ua[2],0.f), fmaxf(ua[3],0.f));
        }
        const s16x8 uf0 = __builtin_bit_cast(s16x8, upk[0]);
        const s16x8 uf1 = __builtin_bit_cast(s16x8, upk[1]);

        // ---- axh[tn] = bh + Wxh.u(s): ONCE per slice (chain-invariant) ----
        f32x4 axh[4];
        #pragma unroll
        for (int tn = 0; tn < 4; ++tn) {
            f32x4 bh4 = *(const f32x4*)&bhs[tn*16 + q*4];   // L1-hit, transient
            axh[tn] = __builtin_amdgcn_mfma_f32_16x16x32_bf16(
                wxhf[tn][0], uf0, bh4, 0, 0, 0);
        }
        #pragma unroll
        for (int tn = 0; tn < 4; ++tn)
            axh[tn] = __builtin_amdgcn_mfma_f32_16x16x32_bf16(
                wxhf[tn][1], uf1, axh[tn], 0, 0, 0);

        // ---- advance every active chain: ti in [s-3, s] (independent!) ----
        #pragma unroll
        for (int ti = 0; ti < TTB; ++ti) {
            if (ti > s || ti < s - (DLAG - 1)) continue;   // compile-time pruned

            f32x4 ha[4];
            if (ti != s) {   // d>0: previous h exists -> add Whh.h_prev
                #pragma unroll
                for (int tn = 0; tn < 4; ++tn) {
                    s16x8 hf0 = __builtin_bit_cast(s16x8, hpk[ti][0]);
                    ha[tn] = __builtin_amdgcn_mfma_f32_16x16x32_bf16(
                        whhf[tn][0], hf0, axh[tn], 0, 0, 0);
                }
                #pragma unroll
                for (int tn = 0; tn < 4; ++tn) {
                    s16x8 hf1 = __builtin_bit_cast(s16x8, hpk[ti][1]);
                    ha[tn] = __builtin_amdgcn_mfma_f32_16x16x32_bf16(
                        whhf[tn][1], hf1, ha[tn], 0, 0, 0);
                }
            } else {         // d==0: h_prev = 0 -> ha is just axh
                #pragma unroll
                for (int tn = 0; tn < 4; ++tn) ha[tn] = axh[tn];
            }

            if (ti > s - (DLAG - 1)) {
                // not the last step of this chain: h = tanh(.), pack for reuse
                #pragma unroll
                for (int tn = 0; tn < 4; ++tn) {
                    hpk[ti][tn>>1][(tn&1)*2+0] =
                        pk2bf(tanh_pre(ha[tn][0]), tanh_pre(ha[tn][1]));
                    hpk[ti][tn>>1][(tn&1)*2+1] =
                        pk2bf(tanh_pre(ha[tn][2]), tanh_pre(ha[tn][3]));
                }
            } else {
                // last step (s == ti+3): y = Wout.h + bout
                float acc = 0.f;
                #pragma unroll
                for (int tn = 0; tn < 4; ++tn) {
                    f32x4 wo = *(const f32x4*)&Wout[tn*16 + q*4];
                    #pragma unroll
                    for (int r = 0; r < 4; ++r)
                        acc += tanh_pre(ha[tn][r]) * wo[r];
                }
                acc += __shfl_xor(acc, 16, 64);
                acc += __shfl_xor(acc, 32, 64);
                if (lane < 16)
                    out[(size_t)(tt0 + ti + DLAG) * NG + G0 + wrow0 + lane] =
                        acc + boutf;
            }
        }

        xf = xf_nxt;
    }
}

extern "C" void kernel_launch(void* const* d_in, const int* in_sizes, int n_in,
                              void* d_out, int out_size, void* d_ws, size_t ws_size,
                              hipStream_t stream) {
    const float* x    = (const float*)d_in[0];
    const float* Win  = (const float*)d_in[1];
    const float* bin  = (const float*)d_in[2];
    const float* Wxh  = (const float*)d_in[3];
    const float* Whh  = (const float*)d_in[4];
    const float* bh   = (const float*)d_in[5];
    const float* Wout = (const float*)d_in[6];
    const float* bout = (const float*)d_in[7];
    float* out = (float*)d_out;
    unsigned short* ws = (unsigned short*)d_ws;

    pack_weights<<<dim3(1), dim3(256), 0, stream>>>(Wxh, Whh, bh, ws);

    dim3 grid(NG / GBLK, TOUTN / TTB);  // (32, 127)
    narx_kernel<<<grid, dim3(256), 0, stream>>>(x, Win, bin, ws, Wout, bout, out);
}

// Round 12
// 180.362 us; speedup vs baseline: 3.9007x; 3.9007x over previous
//
#include <hip/hip_runtime.h>
#include <hip/hip_bf16.h>

// NARX RNN. Inputs fp32, compute bf16 MFMA 16x16x32, output fp32.
// SKEWED schedule (u(s) once per slice, all active chains) + factored
// axh = bh + Wxh.u. R10 verified: 5 waves/SIMD via wxh/whh->LDS + 1-slot
// h ring + hrA/hrB register h-states, 106us, but with ~16MB residual
// scratch (demand ~106 vs the 102-reg cap at (256,5)).
// R11 falsified the pool model: unified file = 512 regs/SIMD (caps:
// 170@3w, 128@4w, 102@5w, 64@8w) -- 8 waves impossible for this kernel.
// R12 = R10 minus the xf PREFETCH double-state (xf+xf_nxt 16 regs -> 8):
//   at ~4.6 waves/SIMD the per-slice x-load latency (~200-900cyc vs
//   ~2000cyc slice body) is TLP-covered; prefetch was a 2.4-wave-era fix.
//   Demand ~98 <= 102 -> spill-free at 5 waves.
// Layout math (verified R0-R10):
//   C/D layout: lane (col=lane&15, q=lane>>4) holds rows 16tn+4q+r; natural
//   pair packing + pi(p)-permuted W^T staging makes packed frags valid as
//   next B operand. pi(p) = 32(p>>5)+16((p>>2)&1)+4((p>>3)&3)+(p&3).
//   bin folded into u-MFMA K slot 16 (q==2 lanes carry bf16(1.0)).
//   Hazards: ascending ti = descending d; d=3 reads s_hpk before d=2
//   rewrites (same-thread LDS program-ordered); d=2 reads hrB before d=1
//   rewrites; d=1 reads hrA before d=0 rewrites (SSA).
// s_win stride 40; pad slots 17..31 zeroed. 2*log2(e) folded into weights.
// tanh = raw v_exp + rcp (pre-scaled input; graceful underflow).

#define NG    2048
#define NXF   16
#define HIDN  64
#define DLAG  4
#define TOUTN 508
#define GBLK  64    // g rows per block (4 waves x 16)
#define TTB   4     // outputs per block
#define NSLC  (DLAG + TTB - 1)   // 7 slices per block
#define STR   72    // setup-kernel staging stride (shorts)
#define SW    40    // resident Win^T stride (shorts), 80B = 16B-aligned rows
#define SCALE 2.8853900817779268f   // 2*log2(e)
#define WXH_OFF 0       // ws: wxh frags, [frag f=tn*2+kk][lane]*8 layout
#define WHH_OFF 4096    // ws: whh frags, [frag f=tn*2+kk][lane]*8 layout
#define BH_OFF  8192    // ws: scaled bh, fp32

typedef short  s16x8 __attribute__((ext_vector_type(8)));
typedef float  f32x4 __attribute__((ext_vector_type(4)));
typedef unsigned int u32x4 __attribute__((ext_vector_type(4)));

__device__ __forceinline__ unsigned short f2bf(float f) {  // RTNE (init only)
    unsigned int u = __float_as_uint(f);
    u += 0x7fffu + ((u >> 16) & 1u);
    return (unsigned short)(u >> 16);
}
__device__ __forceinline__ unsigned int pk2bf(float a, float b) {  // [lo=a, hi=b]
    union { __hip_bfloat162 h2; unsigned int u; } c;
    c.h2 = __float22bfloat162_rn(float2{a, b});
    return c.u;
}
__device__ __forceinline__ float raw_exp2(float a) {
#if __has_builtin(__builtin_amdgcn_exp2f)
    return __builtin_amdgcn_exp2f(a);
#else
    float r;
    asm("v_exp_f32 %0, %1" : "=v"(r) : "v"(a));
    return r;
#endif
}
__device__ __forceinline__ float tanh_pre(float a) {
    // a is already scaled by 2*log2(e) (folded into weights/bias)
    float e = raw_exp2(a);
    return fmaf(-2.0f, __builtin_amdgcn_rcpf(e + 1.0f), 1.0f);
}

// ---- setup: pack Wxh/Whh MFMA fragments (pi-permuted, scaled) + scaled bh ----
__global__ __launch_bounds__(256, 1)
void pack_weights(const float* __restrict__ Wxh,
                  const float* __restrict__ Whh,
                  const float* __restrict__ bh,
                  unsigned short* __restrict__ ws)
{
    __shared__ unsigned short s_stage[HIDN * STR];
    const int tid  = threadIdx.x;
    const int lane = tid & 63;
    const int lm   = lane & 15;
    const int q    = lane >> 4;
    const int p0   = tid >> 2;
    const int pi0  = 32*(p0>>5) + 16*((p0>>2)&1) + 4*((p0>>3)&3) + (p0&3);
    const int n0   = (tid & 3) * 16;

    if (tid < 64) {
        float* bhs = (float*)(ws + BH_OFF);
        bhs[tid] = bh[tid] * SCALE;
    }

    {
        const float* src = Wxh + pi0 * HIDN + n0;
        #pragma unroll
        for (int i = 0; i < 16; ++i)
            s_stage[(n0 + i) * STR + p0] = f2bf(src[i] * SCALE);
    }
    __syncthreads();
    if (tid < 64) {
        #pragma unroll
        for (int tn = 0; tn < 4; ++tn)
            #pragma unroll
            for (int kk = 0; kk < 2; ++kk)
                *(s16x8*)&ws[WXH_OFF + ((tn*2 + kk)*64 + lane)*8] =
                    *(const s16x8*)&s_stage[(tn*16 + lm) * STR + kk*32 + q*8];
    }
    __syncthreads();
    {
        const float* src = Whh + pi0 * HIDN + n0;
        #pragma unroll
        for (int i = 0; i < 16; ++i)
            s_stage[(n0 + i) * STR + p0] = f2bf(src[i] * SCALE);
    }
    __syncthreads();
    if (tid < 64) {
        #pragma unroll
        for (int tn = 0; tn < 4; ++tn)
            #pragma unroll
            for (int kk = 0; kk < 2; ++kk)
                *(s16x8*)&ws[WHH_OFF + ((tn*2 + kk)*64 + lane)*8] =
                    *(const s16x8*)&s_stage[(tn*16 + lm) * STR + kk*32 + q*8];
    }
}

__global__ __launch_bounds__(256, 5)
void narx_kernel(const float* __restrict__ x,
                 const float* __restrict__ Win,
                 const float* __restrict__ bin_g,
                 const unsigned short* __restrict__ wfrag,
                 const float* __restrict__ Wout,
                 const float* __restrict__ bout_g,
                 float* __restrict__ out)
{
    __shared__ unsigned short s_win[HIDN * SW];   // resident Win^T + bin row
    __shared__ unsigned short s_wxh[4096];        // Wxh frags [f][lane]*8
    __shared__ unsigned short s_whh[4096];        // Whh frags [f][lane]*8
    __shared__ float          s_bh[HIDN];         // scaled bh
    __shared__ u32x4          s_hpk[2][256];      // h (d=2->3 only): [half][tid]

    const int tid   = threadIdx.x;
    const int lane  = tid & 63;
    const int lm    = lane & 15;
    const int q     = lane >> 4;
    const int G0    = blockIdx.x * GBLK;
    const int tt0   = blockIdx.y * TTB;
    const int wrow0 = (tid >> 6) * 16;
    const int myg   = G0 + wrow0 + lm;

    // zero the t<DLAG head of the output (poisoned before every launch)
    if (blockIdx.y == 0 && tid < GBLK) {
        #pragma unroll
        for (int t2 = 0; t2 < DLAG; ++t2)
            out[t2 * NG + G0 + tid] = 0.0f;
    }

    // ---- stage wxh/whh frags + scaled bh into LDS ----
    #pragma unroll
    for (int i = 0; i < 2; ++i) {
        *(s16x8*)&s_wxh[(tid + i*256)*8] =
            *(const s16x8*)&wfrag[WXH_OFF + (tid + i*256)*8];
        *(s16x8*)&s_whh[(tid + i*256)*8] =
            *(const s16x8*)&wfrag[WHH_OFF + (tid + i*256)*8];
    }
    if (tid < HIDN) s_bh[tid] = ((const float*)(wfrag + BH_OFF))[tid];

    // ---- build s_win: slots k<16 = Win^T, slot 16 = bin, 17..31 = 0 ----
    {
        int r = tid >> 2, c0 = 16 + (tid & 3) * 4;
        #pragma unroll
        for (int i = 0; i < 4; ++i) {
            unsigned short v = 0;
            if (c0 + i == 16) v = f2bf(bin_g[r]);
            s_win[r * SW + c0 + i] = v;
        }
    }
    {
        int k = tid >> 4, nn = (tid & 15) * 4;
        const float* src = Win + k * HIDN + nn;
        #pragma unroll
        for (int i = 0; i < 4; ++i) s_win[(nn + i) * SW + k] = f2bf(src[i]);
    }

    const float boutf = bout_g[0];
    __syncthreads();   // all LDS staging done

    // ---- skewed hot loop over slices tt0 .. tt0+6 ----
    const size_t slcstride = (size_t)NG * NXF;
    const float* px = x + ((size_t)tt0 * NG + myg) * NXF + q * 8;

    // load + pack slice s into a ready B-frag (q==2 carries the bias 1.0)
    auto load_pack = [&](int s) -> s16x8 {
        s16x8 r = {0,0,0,0,0,0,0,0};
        if (q == 2) r[0] = (short)0x3F80;   // bf16(1.0) at k=16 -> +bin
        if (q < 2) {   // features k = q*8+j < 16
            const float* p = px + (size_t)s * slcstride;
            f32x4 a = *(const f32x4*)p;
            f32x4 b = *(const f32x4*)(p + 4);
            u32x4 xi;
            xi[0] = pk2bf(a[0], a[1]);
            xi[1] = pk2bf(a[2], a[3]);
            xi[2] = pk2bf(b[0], b[1]);
            xi[3] = pk2bf(b[2], b[3]);
            r = __builtin_bit_cast(s16x8, xi);
        }
        return r;
    };

    u32x4 hrA0, hrA1;   // h written at d=0, read at d=1 (registers)
    u32x4 hrB0, hrB1;   // h written at d=1, read at d=2 (registers)

    #pragma unroll
    for (int s = 0; s < NSLC; ++s) {
        // per-slice compiler barrier: LDS-sourced values (s_win, s_wxh,
        // s_whh, s_bh, s_hpk) must be re-loaded this slice -- no
        // cross-slice register residency. SSA register state (hrA/hrB)
        // is unaffected.
        __asm__ __volatile__("" ::: "memory");

        // x slice load (issues early within the slice; latency TLP-covered
        // at ~4.6 waves/SIMD -- prefetch double-state dropped to kill the
        // R10 residual spill: 16 -> 8 regs of x state)
        s16x8 xf = load_pack(s);

        // ---- u(s) = relu(x_s @ Win + bin), computed once, packed bf16 ----
        u32x4 upk[2];
        #pragma unroll
        for (int tj = 0; tj < 4; ++tj) {
            s16x8 wf = *(const s16x8*)&s_win[(tj*16 + lm) * SW + q*8];
            f32x4 zc = {0.f, 0.f, 0.f, 0.f};
            f32x4 ua = __builtin_amdgcn_mfma_f32_16x16x32_bf16(wf, xf, zc, 0, 0, 0);
            upk[tj>>1][(tj&1)*2+0] = pk2bf(fmaxf(ua[0],0.f), fmaxf(ua[1],0.f));
            upk[tj>>1][(tj&1)*2+1] = pk2bf(fmaxf(ua[2],0.f), fmaxf(ua[3],0.f));
        }
        const s16x8 uf0 = __builtin_bit_cast(s16x8, upk[0]);
        const s16x8 uf1 = __builtin_bit_cast(s16x8, upk[1]);

        // ---- axh[tn] = bh + Wxh.u(s): ONCE per slice (chain-invariant) ----
        f32x4 axh[4];
        #pragma unroll
        for (int tn = 0; tn < 4; ++tn) {
            f32x4 bh4 = *(const f32x4*)&s_bh[tn*16 + q*4];
            axh[tn] = __builtin_amdgcn_mfma_f32_16x16x32_bf16(
                *(const s16x8*)&s_wxh[((tn*2 + 0)*64 + lane)*8],
                uf0, bh4, 0, 0, 0);
        }
        #pragma unroll
        for (int tn = 0; tn < 4; ++tn)
            axh[tn] = __builtin_amdgcn_mfma_f32_16x16x32_bf16(
                *(const s16x8*)&s_wxh[((tn*2 + 1)*64 + lane)*8],
                uf1, axh[tn], 0, 0, 0);

        // ---- advance active chains ti in [s-3, s], ASCENDING (= d DESC).
        #pragma unroll
        for (int ti = 0; ti < TTB; ++ti) {
            if (ti > s || ti < s - (DLAG - 1)) continue;   // compile-time pruned
            const int d = s - ti;

            f32x4 ha[4];
            if (d > 0) {   // previous h exists -> add Whh.h_prev
                s16x8 hf0, hf1;
                if (d == 1) {
                    hf0 = __builtin_bit_cast(s16x8, hrA0);
                    hf1 = __builtin_bit_cast(s16x8, hrA1);
                } else if (d == 2) {
                    hf0 = __builtin_bit_cast(s16x8, hrB0);
                    hf1 = __builtin_bit_cast(s16x8, hrB1);
                } else {    // d == 3: from the LDS slot
                    hf0 = __builtin_bit_cast(s16x8, s_hpk[0][tid]);
                    hf1 = __builtin_bit_cast(s16x8, s_hpk[1][tid]);
                }
                #pragma unroll
                for (int tn = 0; tn < 4; ++tn)
                    ha[tn] = __builtin_amdgcn_mfma_f32_16x16x32_bf16(
                        *(const s16x8*)&s_whh[((tn*2 + 0)*64 + lane)*8],
                        hf0, axh[tn], 0, 0, 0);
                #pragma unroll
                for (int tn = 0; tn < 4; ++tn)
                    ha[tn] = __builtin_amdgcn_mfma_f32_16x16x32_bf16(
                        *(const s16x8*)&s_whh[((tn*2 + 1)*64 + lane)*8],
                        hf1, ha[tn], 0, 0, 0);
            } else {       // d==0: h_prev = 0 -> ha is just axh
                #pragma unroll
                for (int tn = 0; tn < 4; ++tn) ha[tn] = axh[tn];
            }

            if (d < DLAG - 1) {
                // not the last step: h = tanh(.), pack
                u32x4 nh0, nh1;
                nh0[0] = pk2bf(tanh_pre(ha[0][0]), tanh_pre(ha[0][1]));
                nh0[1] = pk2bf(tanh_pre(ha[0][2]), tanh_pre(ha[0][3]));
                nh0[2] = pk2bf(tanh_pre(ha[1][0]), tanh_pre(ha[1][1]));
                nh0[3] = pk2bf(tanh_pre(ha[1][2]), tanh_pre(ha[1][3]));
                nh1[0] = pk2bf(tanh_pre(ha[2][0]), tanh_pre(ha[2][1]));
                nh1[1] = pk2bf(tanh_pre(ha[2][2]), tanh_pre(ha[2][3]));
                nh1[2] = pk2bf(tanh_pre(ha[3][0]), tanh_pre(ha[3][1]));
                nh1[3] = pk2bf(tanh_pre(ha[3][2]), tanh_pre(ha[3][3]));
                if (d == 0)      { hrA0 = nh0; hrA1 = nh1; }
                else if (d == 1) { hrB0 = nh0; hrB1 = nh1; }
                else             { s_hpk[0][tid] = nh0; s_hpk[1][tid] = nh1; }
            } else {
                // last step (d == 3): y = Wout.h + bout
                float acc = 0.f;
                #pragma unroll
                for (int tn = 0; tn < 4; ++tn) {
                    f32x4 wo = *(const f32x4*)&Wout[tn*16 + q*4];
                    #pragma unroll
                    for (int r = 0; r < 4; ++r)
                        acc += tanh_pre(ha[tn][r]) * wo[r];
                }
                acc += __shfl_xor(acc, 16, 64);
                acc += __shfl_xor(acc, 32, 64);
                if (lane < 16)
                    out[(size_t)(tt0 + ti + DLAG) * NG + G0 + wrow0 + lane] =
                        acc + boutf;
            }
        }
    }
}

extern "C" void kernel_launch(void* const* d_in, const int* in_sizes, int n_in,
                              void* d_out, int out_size, void* d_ws, size_t ws_size,
                              hipStream_t stream) {
    const float* x    = (const float*)d_in[0];
    const float* Win  = (const float*)d_in[1];
    const float* bin  = (const float*)d_in[2];
    const float* Wxh  = (const float*)d_in[3];
    const float* Whh  = (const float*)d_in[4];
    const float* bh   = (const float*)d_in[5];
    const float* Wout = (const float*)d_in[6];
    const float* bout = (const float*)d_in[7];
    float* out = (float*)d_out;
    unsigned short* ws = (unsigned short*)d_ws;

    pack_weights<<<dim3(1), dim3(256), 0, stream>>>(Wxh, Whh, bh, ws);

    dim3 grid(NG / GBLK, TOUTN / TTB);  // (32, 127)
    narx_kernel<<<grid, dim3(256), 0, stream>>>(x, Win, bin, ws, Wout, bout, out);
}